// Round 9
// baseline (13132.263 us; speedup 1.0000x reference)
//
#include <hip/hip_runtime.h>
#include <cstdint>
#include <cstddef>

// SingleLayerLSTM: B=128, T=2048, D=64, H=256, O=32.
// v9: MFMA re-decomposition. Block = (channel-slice cs of 32 ch, item-slice is
// of 16 items); grid 8x8 = 64 blocks (all trivially co-resident -> no deadlock
// mode). Per step each block computes D(128 gate-outs x 16 items) =
// W(128x320) . x(320x16) with v_mfma_f32_16x16x32_f16:
//  - 4 MFMA waves (1/SIMD), wave w owns out-tiles 2w,2w+1. A = weights,
//    register-resident f16x8 frags (80 VGPR). B = x from LDS, SHARED by the
//    wave's 2 out-tiles -> only 10 ds_read_b128/wave/step.
//  - W rows arranged so tile row = ch_local*4 + gate: each lane's 4 D regs =
//    (f,i,z,r) of ONE channel for ONE item -> activations + c,h update fully
//    in-lane, no reduction. Bias preloaded into the MFMA C operand.
//  - 4 staging waves: poll tagged exchange words, assemble x_{s+1} in LDS
//    (item-major xT[16][336] hw, stride 336 -> b128 reads conflict-free),
//    prefetch+write u_{s+1}, and (cs==0, waves 4/5) compute y_{s-1} =
//    h_s @ W_out as 8 more MFMAs reusing the same B-fragment layout.
//  - Exchange: xh[parity][256 ch][128 it] u32 = (tag s+1)<<16 | fp16(h);
//    relaxed agent atomics only. 0xAA poison tag never matches -> no init,
//    graph-replay safe. Skew <= 2 by transitive step dependency.
//  - ONE __syncthreads per step.

#define HH 256
#define DD 64
#define TT 2048
#define OO 32

typedef _Float16 f16x2 __attribute__((ext_vector_type(2)));
typedef _Float16 f16x8 __attribute__((ext_vector_type(8)));
typedef float    f32x4 __attribute__((ext_vector_type(4)));

__device__ __forceinline__ int pk(float a, float b) {
  f16x2 v; v.x = (_Float16)a; v.y = (_Float16)b;
  return __builtin_bit_cast(int, v);
}
__device__ __forceinline__ float frcp(float x) { return __builtin_amdgcn_rcpf(x); }
__device__ __forceinline__ float sigm(float x)  { return frcp(1.0f + __expf(-x)); }
__device__ __forceinline__ float tanhf_(float x){ return 1.0f - 2.0f * frcp(1.0f + __expf(2.0f * x)); }

__global__ __launch_bounds__(512, 2)
void lstm_mfma(const float* __restrict__ u,    const float* __restrict__ x0,
               const float* __restrict__ kfiz, const float* __restrict__ bfiz,
               const float* __restrict__ kr,   const float* __restrict__ br,
               const float* __restrict__ wout, const float* __restrict__ bout,
               float* __restrict__ out, unsigned int* __restrict__ xh)
{
  const int tid  = threadIdx.x;
  const int cs   = blockIdx.x >> 3;        // channel slice [0,8): ch 32cs..+32
  const int is   = blockIdx.x & 7;         // item slice [0,8): items 16is..+16
  const int wv   = tid >> 6;
  const int lane = tid & 63;
  const int n    = lane & 15;              // MFMA col: item-local
  const int quad = lane >> 4;
  const int itemg = is * 16 + n;           // this lane's frag item (global)

  // x in LDS, item-major, padded: xT[parity][item n][row k], stride 336 hw
  // (336 hw = 168 dw == 8 mod 32 -> b128 reads spread bank-quads evenly).
  __shared__ __align__(16) _Float16 xT[2][16 * 336];

  // -------- init xT[0] = [u_0 | h_0] --------
  if (tid < 256) {
    const int nU = tid >> 4, d4 = (tid & 15) * 4;
    const float4 uv = *(const float4*)&u[((size_t)(is * 16 + nU) * TT) * DD + d4];
    int2 w; w.x = pk(uv.x, uv.y); w.y = pk(uv.z, uv.w);
    *(int2*)&xT[0][nU * 336 + d4] = w;
  }
  {
    const int nH = tid >> 5, ch8 = (tid & 31) * 8;
    const float4 a = *(const float4*)&x0[(size_t)(is * 16 + nH) * 512 + ch8];
    const float4 b = *(const float4*)&x0[(size_t)(is * 16 + nH) * 512 + ch8 + 4];
    int4 w; w.x = pk(a.x, a.y); w.y = pk(a.z, a.w);
    w.z = pk(b.x, b.y); w.w = pk(b.z, b.w);
    *(int4*)&xT[0][nH * 336 + 64 + ch8] = w;
  }

  // -------- per-role setup --------
  // MFMA waves: A-frags (A[m=lane&15][k=quad*8+j], m = ch_local*4+gate),
  // bias in D layout (row=quad*4+reg -> reg = gate), c-state per tile.
  f16x8 wA[2][10];
  f32x4 bias2[2];
  float cst[2];
  int   chD[2];
  if (wv < 4) {
    const int m = lane & 15;
#pragma unroll
    for (int t2 = 0; t2 < 2; ++t2) {
      const int t   = wv * 2 + t2;
      const int gA  = m & 3;
      const int chA = cs * 32 + t * 4 + (m >> 2);
      const float* colA; int strA;
      if (gA < 3) { colA = kfiz + gA * 256 + chA; strA = 768; }
      else        { colA = kr + chA;              strA = 256; }
#pragma unroll
      for (int c = 0; c < 10; ++c)
#pragma unroll
        for (int j = 0; j < 8; ++j)
          wA[t2][c][j] = (_Float16)colA[(size_t)(c * 32 + quad * 8 + j) * strA];
      chD[t2] = cs * 32 + t * 4 + quad;
      f32x4 bb;
      bb[0] = bfiz[0 * 256 + chD[t2]];
      bb[1] = bfiz[1 * 256 + chD[t2]];
      bb[2] = bfiz[2 * 256 + chD[t2]];
      bb[3] = br[chD[t2]];
      bias2[t2] = bb;
      cst[t2] = x0[(size_t)itemg * 512 + 256 + chD[t2]];
    }
  }
  // Staging waves: poll map (lane -> 1 item x 16 channels), u-prefetch map,
  // y W_out frags on cs==0 waves 4/5.
  const int sl  = tid - 256;               // valid for wv>=4
  const int nP  = sl & 15, cb = sl >> 4;   // poll: item nP, channels 16cb..+16
  const int nU2 = sl >> 4, d4u = (sl & 15) * 4;
  f16x8 wy[8];
  f32x4 biasy;
  const int ot = wv - 4;
  if (wv >= 4 && wv < 6 && cs == 0) {
    const int m  = lane & 15;
    const int oA = ot * 16 + m;
#pragma unroll
    for (int cy = 0; cy < 8; ++cy)
#pragma unroll
      for (int j = 0; j < 8; ++j)
        wy[cy][j] = (_Float16)wout[(size_t)(cy * 32 + quad * 8 + j) * OO + oA];
    const int oD = ot * 16 + quad * 4;
    f32x4 bb; bb[0] = bout[oD]; bb[1] = bout[oD + 1];
    bb[2] = bout[oD + 2]; bb[3] = bout[oD + 3];
    biasy = bb;
  }

  __syncthreads();

  for (int s = 0; s < TT; ++s) {
    const int cur = s & 1, nxt = cur ^ 1;

    if (wv < 4) {
      // ---- GEMM fragment + gates ----
      f32x4 a0 = bias2[0], a1 = bias2[1];
#pragma unroll
      for (int c = 0; c < 10; ++c) {
        const f16x8 bb = *(const f16x8*)&xT[cur][n * 336 + c * 32 + quad * 8];
        a0 = __builtin_amdgcn_mfma_f32_16x16x32_f16(wA[0][c], bb, a0, 0, 0, 0);
        a1 = __builtin_amdgcn_mfma_f32_16x16x32_f16(wA[1][c], bb, a1, 0, 0, 0);
      }
#pragma unroll
      for (int t2 = 0; t2 < 2; ++t2) {
        const f32x4 acc = t2 ? a1 : a0;
        const float f = sigm(acc[0]), i = sigm(acc[1]);
        const float z = sigm(acc[2]), r = tanhf_(acc[3]);
        cst[t2] = f * cst[t2] + i * r;
        const float hn = z * tanhf_(cst[t2]);
        const unsigned hb =
            (unsigned)__builtin_bit_cast(unsigned short, (_Float16)hn);
        __hip_atomic_store(&xh[((size_t)nxt * 256 + chD[t2]) * 128 + itemg],
                           ((unsigned)(s + 1) << 16) | hb,
                           __ATOMIC_RELAXED, __HIP_MEMORY_SCOPE_AGENT);
      }
    } else {
      // ---- staging: u prefetch, y, polls ----
      float4 uv;
      if (s + 1 < TT)
        uv = *(const float4*)&u[((size_t)(is * 16 + nU2) * TT + (s + 1)) * DD + d4u];

      if (wv < 6 && cs == 0 && s >= 1) {   // y_{s-1} = h_s @ W_out + b
        f32x4 ya = biasy;
#pragma unroll
        for (int cy = 0; cy < 8; ++cy) {
          const f16x8 bb = *(const f16x8*)&xT[cur][n * 336 + 64 + cy * 32 + quad * 8];
          ya = __builtin_amdgcn_mfma_f32_16x16x32_f16(wy[cy], bb, ya, 0, 0, 0);
        }
        float4 yo; yo.x = ya[0]; yo.y = ya[1]; yo.z = ya[2]; yo.w = ya[3];
        *(float4*)&out[((size_t)itemg * TT + (s - 1)) * OO + ot * 16 + quad * 4] = yo;
      }

      if (s + 1 < TT) {
        int2 w; w.x = pk(uv.x, uv.y); w.y = pk(uv.z, uv.w);
        *(int2*)&xT[nxt][nU2 * 336 + d4u] = w;
      }

      // polls: lane covers channels 16cb..16cb+15 for item nP
      unsigned got[16];
      unsigned pend = 0xffffu;
      const unsigned want = (unsigned)(s + 1) << 16;
      unsigned int* base = &xh[((size_t)nxt * 256 + cb * 16) * 128 + (is * 16 + nP)];
      do {
#pragma unroll
        for (int j = 0; j < 16; ++j)
          if (pend & (1u << j)) {
            const unsigned v = __hip_atomic_load(base + (size_t)j * 128,
                                                 __ATOMIC_RELAXED,
                                                 __HIP_MEMORY_SCOPE_AGENT);
            if ((v & 0xffff0000u) == want) { got[j] = v; pend &= ~(1u << j); }
          }
      } while (pend);
      int4 w0, w1;
      w0.x = (got[0] & 0xffffu) | (got[1] << 16);
      w0.y = (got[2] & 0xffffu) | (got[3] << 16);
      w0.z = (got[4] & 0xffffu) | (got[5] << 16);
      w0.w = (got[6] & 0xffffu) | (got[7] << 16);
      w1.x = (got[8] & 0xffffu) | (got[9] << 16);
      w1.y = (got[10] & 0xffffu) | (got[11] << 16);
      w1.z = (got[12] & 0xffffu) | (got[13] << 16);
      w1.w = (got[14] & 0xffffu) | (got[15] << 16);
      *(int4*)&xT[nxt][nP * 336 + 64 + cb * 16] = w0;
      *(int4*)&xT[nxt][nP * 336 + 64 + cb * 16 + 8] = w1;
    }

    __syncthreads();   // xT[nxt] fully assembled
  }

  // ---- epilogue: y_{TT-1} from h_TT (assembled in xT[0]) ----
  if (wv >= 4 && wv < 6 && cs == 0) {
    f32x4 ya = biasy;
#pragma unroll
    for (int cy = 0; cy < 8; ++cy) {
      const f16x8 bb = *(const f16x8*)&xT[0][n * 336 + 64 + cy * 32 + quad * 8];
      ya = __builtin_amdgcn_mfma_f32_16x16x32_f16(wy[cy], bb, ya, 0, 0, 0);
    }
    float4 yo; yo.x = ya[0]; yo.y = ya[1]; yo.z = ya[2]; yo.w = ya[3];
    *(float4*)&out[((size_t)itemg * TT + (TT - 1)) * OO + ot * 16 + quad * 4] = yo;
  }
}

extern "C" void kernel_launch(void* const* d_in, const int* in_sizes, int n_in,
                              void* d_out, int out_size, void* d_ws, size_t ws_size,
                              hipStream_t stream) {
  const float* u    = (const float*)d_in[0];
  const float* x0   = (const float*)d_in[1];
  const float* kfiz = (const float*)d_in[2];
  const float* bfiz = (const float*)d_in[3];
  const float* kr   = (const float*)d_in[4];
  const float* br   = (const float*)d_in[5];
  const float* wout = (const float*)d_in[6];
  const float* bout = (const float*)d_in[7];
  float* out = (float*)d_out;
  // ws: xh[2 parity][256 ch][128 it] u32 = 256 KB. 0xAA poison -> tag 0xAAAA
  // never matches a version in [1,2048] -> no init needed, replay-safe.
  unsigned int* xh = (unsigned int*)d_ws;
  lstm_mfma<<<dim3(64), dim3(512), 0, stream>>>(
      u, x0, kfiz, bfiz, kr, br, wout, bout, out, xh);
}

// Round 10
// 3951.268 us; speedup vs baseline: 3.3236x; 3.3236x over previous
//
#include <hip/hip_runtime.h>
#include <cstdint>
#include <cstddef>

// SingleLayerLSTM: B=128, T=2048, D=64, H=256, O=32.
// v10 = v8 with the two items a CU serves MERGED into one block.
// R9 lesson: v9's 64-block MFMA layout idled 75% of CUs and exposed raw
// exchange latency -> 13ms. Reverted to the v8 quad-split structure.
// R8 counters: CU served 2 items via 2 lockstep blocks, paying barriers,
// poll RT and the max-of-4 convoy TWICE per step (VALUBusy 36%). Here:
//  - 256 blocks x 512 thr, 1 block/CU; item-pair g2 = blk>>2, quarter
//    q4 = blk&3 (4 CONTIGUOUS blocks per group -> residency-safe).
//  - Thread (c = tid>>3, rq = tid&7) owns channel q4*64+c, all 4 gates,
//    rows u8/own8/partner24 -> 80 fp16-pair VGPRs SHARED by both items;
//    per step does the dot for item0 and item1 (160 fdot2).
//  - Exchange: xh[parity][item 128][pair 64..] u64 = (tag s+1)<<32 |
//    (fp16 ch_even | fp16 ch_odd). Relaxed agent atomics only. Poll lanes
//    0..95 item0 / 96..191 item1, one u64 each -> half the L3 requests of
//    v8 per CU, ONE wait window + one barrier pair per step for 2 items.
//    0xAA poison tag never matches -> no init, graph-replay safe.
//  - Shadow work (u+own dots for s+1, y pipeline) as in v8, x2 items.
//  - launch_bounds(512,2): proven 128-VGPR cap (R1/R8).

#define HH 256
#define DD 64
#define TT 2048
#define OO 32

typedef _Float16 f16x2 __attribute__((ext_vector_type(2)));

__device__ __forceinline__ f16x2 b2h(int v) { return __builtin_bit_cast(f16x2, v); }
__device__ __forceinline__ int h2b(f16x2 v) { return __builtin_bit_cast(int, v); }
__device__ __forceinline__ unsigned pk32(float a, float b) {
  f16x2 v; v.x = (_Float16)a; v.y = (_Float16)b;
  return __builtin_bit_cast(unsigned, v);
}

#if __has_builtin(__builtin_amdgcn_fdot2)
__device__ __forceinline__ float fdot2(f16x2 a, f16x2 b, float c) {
  return __builtin_amdgcn_fdot2(a, b, c, false);
}
#else
__device__ __forceinline__ float fdot2(f16x2 a, f16x2 b, float c) {
  return fmaf((float)a.y, (float)b.y, fmaf((float)a.x, (float)b.x, c));
}
#endif

__device__ __forceinline__ float frcp(float x) { return __builtin_amdgcn_rcpf(x); }
__device__ __forceinline__ float sigm(float x)  { return frcp(1.0f + __expf(-x)); }
__device__ __forceinline__ float tanhf_(float x){ return 1.0f - 2.0f * frcp(1.0f + __expf(2.0f * x)); }

#define XOR_ADD8(x) do { \
  x += __shfl_xor(x, 1); x += __shfl_xor(x, 2); x += __shfl_xor(x, 4); \
} while (0)

// u(8 rows) + own-h(8 rows) partial for one item; overwrites F,I,Z,R
#define UOWN(X, F, I, Z, R) do { \
  const int4 uv_ = *(const int4*)&(X)[rq * 8]; \
  const int4 ov_ = *(const int4*)&(X)[64 + rq * 8]; \
  f16x2 u0_=b2h(uv_.x),u1_=b2h(uv_.y),u2_=b2h(uv_.z),u3_=b2h(uv_.w); \
  f16x2 o0_=b2h(ov_.x),o1_=b2h(ov_.y),o2_=b2h(ov_.z),o3_=b2h(ov_.w); \
  F = fdot2(b2h(w2u[ 0]),u0_,0.0f); F = fdot2(b2h(w2u[ 1]),u1_,F); \
  F = fdot2(b2h(w2u[ 2]),u2_,F);    F = fdot2(b2h(w2u[ 3]),u3_,F); \
  F = fdot2(b2h(w2o[ 0]),o0_,F);    F = fdot2(b2h(w2o[ 1]),o1_,F); \
  F = fdot2(b2h(w2o[ 2]),o2_,F);    F = fdot2(b2h(w2o[ 3]),o3_,F); \
  I = fdot2(b2h(w2u[ 4]),u0_,0.0f); I = fdot2(b2h(w2u[ 5]),u1_,I); \
  I = fdot2(b2h(w2u[ 6]),u2_,I);    I = fdot2(b2h(w2u[ 7]),u3_,I); \
  I = fdot2(b2h(w2o[ 4]),o0_,I);    I = fdot2(b2h(w2o[ 5]),o1_,I); \
  I = fdot2(b2h(w2o[ 6]),o2_,I);    I = fdot2(b2h(w2o[ 7]),o3_,I); \
  Z = fdot2(b2h(w2u[ 8]),u0_,0.0f); Z = fdot2(b2h(w2u[ 9]),u1_,Z); \
  Z = fdot2(b2h(w2u[10]),u2_,Z);    Z = fdot2(b2h(w2u[11]),u3_,Z); \
  Z = fdot2(b2h(w2o[ 8]),o0_,Z);    Z = fdot2(b2h(w2o[ 9]),o1_,Z); \
  Z = fdot2(b2h(w2o[10]),o2_,Z);    Z = fdot2(b2h(w2o[11]),o3_,Z); \
  R = fdot2(b2h(w2u[12]),u0_,0.0f); R = fdot2(b2h(w2u[13]),u1_,R); \
  R = fdot2(b2h(w2u[14]),u2_,R);    R = fdot2(b2h(w2u[15]),u3_,R); \
  R = fdot2(b2h(w2o[12]),o0_,R);    R = fdot2(b2h(w2o[13]),o1_,R); \
  R = fdot2(b2h(w2o[14]),o2_,R);    R = fdot2(b2h(w2o[15]),o3_,R); \
} while (0)

// partner-h (24 rows) accumulate into F,I,Z,R
#define PDOT(X, F, I, Z, R) do { \
  const int4* pp_ = (const int4*)&(X)[128 + rq * 24]; \
  int4 v0_ = pp_[0], v1_ = pp_[1], v2_ = pp_[2]; \
  f16x2 h0_=b2h(v0_.x),h1_=b2h(v0_.y),h2_ =b2h(v0_.z),h3_ =b2h(v0_.w); \
  f16x2 h4_=b2h(v1_.x),h5_=b2h(v1_.y),h6_ =b2h(v1_.z),h7_ =b2h(v1_.w); \
  f16x2 h8_=b2h(v2_.x),h9_=b2h(v2_.y),h10_=b2h(v2_.z),h11_=b2h(v2_.w); \
  F=fdot2(b2h(w2p[ 0]),h0_,F); F=fdot2(b2h(w2p[ 1]),h1_,F); \
  F=fdot2(b2h(w2p[ 2]),h2_,F); F=fdot2(b2h(w2p[ 3]),h3_,F); \
  F=fdot2(b2h(w2p[ 4]),h4_,F); F=fdot2(b2h(w2p[ 5]),h5_,F); \
  F=fdot2(b2h(w2p[ 6]),h6_,F); F=fdot2(b2h(w2p[ 7]),h7_,F); \
  F=fdot2(b2h(w2p[ 8]),h8_,F); F=fdot2(b2h(w2p[ 9]),h9_,F); \
  F=fdot2(b2h(w2p[10]),h10_,F);F=fdot2(b2h(w2p[11]),h11_,F); \
  I=fdot2(b2h(w2p[12]),h0_,I); I=fdot2(b2h(w2p[13]),h1_,I); \
  I=fdot2(b2h(w2p[14]),h2_,I); I=fdot2(b2h(w2p[15]),h3_,I); \
  I=fdot2(b2h(w2p[16]),h4_,I); I=fdot2(b2h(w2p[17]),h5_,I); \
  I=fdot2(b2h(w2p[18]),h6_,I); I=fdot2(b2h(w2p[19]),h7_,I); \
  I=fdot2(b2h(w2p[20]),h8_,I); I=fdot2(b2h(w2p[21]),h9_,I); \
  I=fdot2(b2h(w2p[22]),h10_,I);I=fdot2(b2h(w2p[23]),h11_,I); \
  Z=fdot2(b2h(w2p[24]),h0_,Z); Z=fdot2(b2h(w2p[25]),h1_,Z); \
  Z=fdot2(b2h(w2p[26]),h2_,Z); Z=fdot2(b2h(w2p[27]),h3_,Z); \
  Z=fdot2(b2h(w2p[28]),h4_,Z); Z=fdot2(b2h(w2p[29]),h5_,Z); \
  Z=fdot2(b2h(w2p[30]),h6_,Z); Z=fdot2(b2h(w2p[31]),h7_,Z); \
  Z=fdot2(b2h(w2p[32]),h8_,Z); Z=fdot2(b2h(w2p[33]),h9_,Z); \
  Z=fdot2(b2h(w2p[34]),h10_,Z);Z=fdot2(b2h(w2p[35]),h11_,Z); \
  R=fdot2(b2h(w2p[36]),h0_,R); R=fdot2(b2h(w2p[37]),h1_,R); \
  R=fdot2(b2h(w2p[38]),h2_,R); R=fdot2(b2h(w2p[39]),h3_,R); \
  R=fdot2(b2h(w2p[40]),h4_,R); R=fdot2(b2h(w2p[41]),h5_,R); \
  R=fdot2(b2h(w2p[42]),h6_,R); R=fdot2(b2h(w2p[43]),h7_,R); \
  R=fdot2(b2h(w2p[44]),h8_,R); R=fdot2(b2h(w2p[45]),h9_,R); \
  R=fdot2(b2h(w2p[46]),h10_,R);R=fdot2(b2h(w2p[47]),h11_,R); \
} while (0)

// y-partials for one item from the permuted h region of X
#define YPART(X, OUTSLOT) do { \
  const int2* hq_ = (const int2*)&(X)[64 + jc * 16]; \
  int2 h0_ = hq_[0], h1_ = hq_[1], h2_ = hq_[2], h3_ = hq_[3]; \
  const int4* wp_ = (const int4*)&wopk[(jc * 8 + o) * 8]; \
  int4 wa_ = wp_[0], wb_ = wp_[1]; \
  float ya_ = 0.0f; \
  ya_ = fdot2(b2h(wa_.x), b2h(h0_.x), ya_); \
  ya_ = fdot2(b2h(wa_.y), b2h(h0_.y), ya_); \
  ya_ = fdot2(b2h(wa_.z), b2h(h1_.x), ya_); \
  ya_ = fdot2(b2h(wa_.w), b2h(h1_.y), ya_); \
  ya_ = fdot2(b2h(wb_.x), b2h(h2_.x), ya_); \
  ya_ = fdot2(b2h(wb_.y), b2h(h2_.y), ya_); \
  ya_ = fdot2(b2h(wb_.z), b2h(h3_.x), ya_); \
  ya_ = fdot2(b2h(wb_.w), b2h(h3_.y), ya_); \
  OUTSLOT = ya_; \
} while (0)

__global__ __launch_bounds__(512, 2)
void lstm_pair(const float* __restrict__ u,    const float* __restrict__ x0,
               const float* __restrict__ kfiz, const float* __restrict__ bfiz,
               const float* __restrict__ kr,   const float* __restrict__ br,
               const float* __restrict__ wout, const float* __restrict__ bout,
               float* __restrict__ out, unsigned long long* __restrict__ xh)
{
  const int tid = threadIdx.x;
  const int g2  = blockIdx.x >> 2;         // item pair: items 2g2, 2g2+1
  const int q4  = blockIdx.x & 3;          // quarter
  const int c   = tid >> 3;                // channel within quarter [0,64)
  const int rq  = tid & 7;                 // row slice
  const int cg  = q4 * 64 + c;             // global channel

  // per (parity,item): [0,64) u | [64,128) own h | [128,320) partner h (P-order)
  __shared__ __align__(16) _Float16 uh[2][2][320];
  __shared__ float yred[2][2][8][17];
  __shared__ __align__(16) int wopk[1024];

  // ---- register-resident weights (80 pairs, shared by both items) ----
  int w2u[16], w2o[16], w2p[48];
#pragma unroll
  for (int g = 0; g < 4; ++g) {
    const float* colp = (g < 3) ? (kfiz + g * HH + cg) : (kr + cg);
    const int cst = (g < 3) ? 3 * HH : HH;
#pragma unroll
    for (int k = 0; k < 4; ++k) {
      f16x2 v;
      v.x = (_Float16)colp[(rq * 8 + 2 * k    ) * cst];
      v.y = (_Float16)colp[(rq * 8 + 2 * k + 1) * cst];
      w2u[g * 4 + k] = h2b(v);
      f16x2 w;
      w.x = (_Float16)colp[(DD + q4 * 64 + rq * 8 + 2 * k    ) * cst];
      w.y = (_Float16)colp[(DD + q4 * 64 + rq * 8 + 2 * k + 1) * cst];
      w2o[g * 4 + k] = h2b(w);
    }
#pragma unroll
    for (int m = 0; m < 12; ++m) {
      const int j0 = rq * 24 + 2 * m, j1 = j0 + 1;
      const int r0 = DD + (j0 < q4 * 64 ? j0 : j0 + 64);
      const int r1 = DD + (j1 < q4 * 64 ? j1 : j1 + 64);
      f16x2 v;
      v.x = (_Float16)colp[r0 * cst];
      v.y = (_Float16)colp[r1 * cst];
      w2p[g * 12 + m] = h2b(v);
    }
  }
  const float bf_ = bfiz[0 * HH + cg];
  const float bi_ = bfiz[1 * HH + cg];
  const float bz_ = bfiz[2 * HH + cg];
  const float br_ = br[cg];

  // ---- W_out staged permuted (block's 8 out cols; item-invariant) ----
  for (int t = tid; t < 1024; t += 512) {
    const int jc = t >> 6, o = (t >> 3) & 7, k = t & 7;
    const int pos0 = jc * 16 + 2 * k, pos1 = pos0 + 1;
    const int ch0 = (pos0 < 64) ? q4 * 64 + pos0
                                : ((pos0 - 64) < q4 * 64 ? pos0 - 64 : pos0);
    const int ch1 = (pos1 < 64) ? q4 * 64 + pos1
                                : ((pos1 - 64) < q4 * 64 ? pos1 - 64 : pos1);
    f16x2 v;
    v.x = (_Float16)wout[ch0 * OO + q4 * 8 + o];
    v.y = (_Float16)wout[ch1 * OO + q4 * 8 + o];
    wopk[t] = h2b(v);
  }
  const float bo = (tid >= 448 && tid < 464) ? bout[q4 * 8 + ((tid - 448) & 7)] : 0.0f;

  // ---- state init ----
  float cs0 = x0[(size_t)(g2 * 2 + 0) * 512 + 256 + cg];
  float cs1 = x0[(size_t)(g2 * 2 + 1) * 512 + 256 + cg];
  {  // h0, permuted; all 512 lanes cover 2 items x 256 ch
    const int it = tid >> 8, ch = tid & 255;
    const int pos = (ch >= q4 * 64 && ch < q4 * 64 + 64)
                        ? 64 + (ch - q4 * 64)
                        : 128 + (ch < q4 * 64 ? ch : ch - 64);
    uh[0][it][pos] = (_Float16)x0[(size_t)(g2 * 2 + it) * 512 + ch];
  }
  if (tid >= 192 && tid < 320) {   // u_0
    const int l = tid - 192;
    uh[0][l >> 6][l & 63] = (_Float16)u[((size_t)(g2 * 2 + (l >> 6)) * TT) * DD + (l & 63)];
  }
  __syncthreads();

  float a0f, a0i, a0z, a0r, a1f, a1i, a1z, a1r;
  UOWN(uh[0][0], a0f, a0i, a0z, a0r);
  UOWN(uh[0][1], a1f, a1i, a1z, a1r);

  for (int s = 0; s < TT; ++s) {
    const int cur = s & 1, nxt = cur ^ 1;

    // u_{s+1} issued early (lanes 192..319)
    float un = 0.0f;
    if (tid >= 192 && tid < 320 && s + 1 < TT) {
      const int l = tid - 192;
      un = u[((size_t)(g2 * 2 + (l >> 6)) * TT + s + 1) * DD + (l & 63)];
    }

    // ---- A: partner dots, both items ----
    PDOT(uh[cur][0], a0f, a0i, a0z, a0r);
    PDOT(uh[cur][1], a1f, a1i, a1z, a1r);

    // ---- B: reduce + activations ----
    XOR_ADD8(a0f); XOR_ADD8(a0i); XOR_ADD8(a0z); XOR_ADD8(a0r);
    XOR_ADD8(a1f); XOR_ADD8(a1i); XOR_ADD8(a1z); XOR_ADD8(a1r);
    const float f0 = sigm(a0f + bf_), i0 = sigm(a0i + bi_);
    const float z0 = sigm(a0z + bz_), r0 = tanhf_(a0r + br_);
    cs0 = f0 * cs0 + i0 * r0;
    const float hn0 = z0 * tanhf_(cs0);
    const float f1 = sigm(a1f + bf_), i1 = sigm(a1i + bi_);
    const float z1 = sigm(a1z + bz_), r1 = tanhf_(a1r + br_);
    cs1 = f1 * cs1 + i1 * r1;
    const float hn1 = z1 * tanhf_(cs1);

    // ---- C: publish (u64, 2 ch/word) + own-h LDS + u_{s+1} LDS ----
    const float hn0n = __shfl_down(hn0, 8);   // channel c+1's value (rq kept)
    const float hn1n = __shfl_down(hn1, 8);
    if (rq == 0) {
      uh[nxt][0][64 + c] = (_Float16)hn0;
      uh[nxt][1][64 + c] = (_Float16)hn1;
      if (!(c & 1)) {
        const int pair = q4 * 32 + (c >> 1);
        const unsigned long long tag = (unsigned long long)(s + 1) << 32;
        __hip_atomic_store(&xh[((size_t)nxt * 128 + g2 * 2 + 0) * 128 + pair],
                           tag | pk32(hn0, hn0n),
                           __ATOMIC_RELAXED, __HIP_MEMORY_SCOPE_AGENT);
        __hip_atomic_store(&xh[((size_t)nxt * 128 + g2 * 2 + 1) * 128 + pair],
                           tag | pk32(hn1, hn1n),
                           __ATOMIC_RELAXED, __HIP_MEMORY_SCOPE_AGENT);
      }
    }
    if (tid >= 192 && tid < 320 && s + 1 < TT) {
      const int l = tid - 192;
      uh[nxt][l >> 6][l & 63] = (_Float16)un;
    }
    __syncthreads();   // B1

    // ---- D: shadow work ----
    if (s >= 2 && tid >= 448 && tid < 464) {          // store y_{s-2}
      const int it = (tid - 448) >> 3, o = (tid - 448) & 7;
      float ssum = bo;
#pragma unroll
      for (int k = 0; k < 16; ++k) ssum += yred[nxt][it][o][k];
      out[((size_t)(g2 * 2 + it) * TT + (s - 2)) * OO + q4 * 8 + o] = ssum;
    }
    if (s >= 1 && tid >= 192 && tid < 448) {          // y partials for s-1
      const int l = tid - 192, it = l >> 7, idx = l & 127;
      const int o = idx & 7, jc = idx >> 3;
      YPART(uh[cur][it], yred[cur][it][o][jc]);
    }
    if (s + 1 < TT) {                                  // u+own partials, s+1
      UOWN(uh[nxt][0], a0f, a0i, a0z, a0r);
      UOWN(uh[nxt][1], a1f, a1i, a1z, a1r);
    }

    // ---- E: poll partner pairs (lanes 0..191, one u64 each) ----
    if (tid < 192) {
      const int it = (tid >= 96) ? 1 : 0;
      const int j  = it ? tid - 96 : tid;              // partner pair [0,96)
      const int pidx = (j < q4 * 32) ? j : j + 32;
      const unsigned want = (unsigned)(s + 1);
      unsigned long long v;
      do {
        v = __hip_atomic_load(&xh[((size_t)nxt * 128 + g2 * 2 + it) * 128 + pidx],
                              __ATOMIC_RELAXED, __HIP_MEMORY_SCOPE_AGENT);
      } while ((unsigned)(v >> 32) != want);
      ((int*)&uh[nxt][it][128])[j] = (int)(unsigned)v;
    }
    __syncthreads();   // B2
  }

  // ---- epilogue: y_{TT-2} from yred[1]; y_{TT-1} from uh[0] ----
  if (tid >= 448 && tid < 464) {
    const int it = (tid - 448) >> 3, o = (tid - 448) & 7;
    float ssum = bo;
#pragma unroll
    for (int k = 0; k < 16; ++k) ssum += yred[1][it][o][k];
    out[((size_t)(g2 * 2 + it) * TT + (TT - 2)) * OO + q4 * 8 + o] = ssum;
  }
  if (tid >= 192 && tid < 448) {
    const int l = tid - 192, it = l >> 7, idx = l & 127;
    const int o = idx & 7, jc = idx >> 3;
    YPART(uh[0][it], yred[0][it][o][jc]);
  }
  __syncthreads();
  if (tid >= 448 && tid < 464) {
    const int it = (tid - 448) >> 3, o = (tid - 448) & 7;
    float ssum = bo;
#pragma unroll
    for (int k = 0; k < 16; ++k) ssum += yred[0][it][o][k];
    out[((size_t)(g2 * 2 + it) * TT + (TT - 1)) * OO + q4 * 8 + o] = ssum;
  }
}

extern "C" void kernel_launch(void* const* d_in, const int* in_sizes, int n_in,
                              void* d_out, int out_size, void* d_ws, size_t ws_size,
                              hipStream_t stream) {
  const float* u    = (const float*)d_in[0];
  const float* x0   = (const float*)d_in[1];
  const float* kfiz = (const float*)d_in[2];
  const float* bfiz = (const float*)d_in[3];
  const float* kr   = (const float*)d_in[4];
  const float* br   = (const float*)d_in[5];
  const float* wout = (const float*)d_in[6];
  const float* bout = (const float*)d_in[7];
  float* out = (float*)d_out;
  // ws: xh[2 parity][128 item][128 pair] u64 = 256 KB. 0xAA poison -> tag
  // 0xAAAAAAAA never matches a version in [1,2048] -> no init, replay-safe.
  unsigned long long* xh = (unsigned long long*)d_ws;
  lstm_pair<<<dim3(256), dim3(512), 0, stream>>>(
      u, x0, kfiz, bfiz, kr, br, wout, bout, out, xh);
}